// Round 4
// baseline (110.748 us; speedup 1.0000x reference)
//
#include <hip/hip_runtime.h>
#include <math.h>

#define N_WIRES 12
#define DEPTH   4
#define NGATES  48
#define IN_DIM  256
#define ROWS_PER_BLOCK 16
#define XSTRIDE 272     // 256 + 16 pad
#define TABSZ   (N_WIRES * 16)  // 192 floats: [w*16+kap]=C, [w*16+8+kap]=D
#define NSLICE  16
#define FLAG_OFF 3072           // u32 index of flags in ws (slices: 0..3071)
#define SENTINEL 0x5EC7A9B1u

// ---- compile-time circuit structure (masks are data-independent) ----
// Gate (d,w): RX after d CNOT-chain layers; folded mask = col w of L^-d.
// L = lower-triangular ones; L^-1 = I+N (N = subdiagonal); L^-d = binomial mod 2.
// Measurement string S_w = row w of L^4 = {w, w-4, w-8} (>=0 only).
struct Tabs {
    unsigned gm[NGATES];          // gate masks
    bool     rel[N_WIRES][NGATES];// gate in G_w iff par(gm & S_w)
    unsigned chi[NGATES];         // bit i = par(gm_low_nibble & i), i=0..15
    unsigned comp[N_WIRES];       // butterfly dims = lane dims not in class
};
constexpr int cparity(unsigned v) { int c = 0; while (v) { c ^= (int)(v & 1u); v >>= 1; } return c; }
constexpr Tabs make_tabs() {
    Tabs tb{};
    for (int g = 0; g < NGATES; ++g) {
        int d = g / N_WIRES, w = g % N_WIRES;
        unsigned m = 1u << w;
        if ((d == 1 || d == 3) && w + 1 < N_WIRES) m |= 1u << (w + 1);
        if ((d == 2 || d == 3) && w + 2 < N_WIRES) m |= 1u << (w + 2);
        if (d == 3 && w + 3 < N_WIRES)             m |= 1u << (w + 3);
        tb.gm[g] = m;
        unsigned c = 0;
        for (int i = 0; i < 16; ++i) c |= (unsigned)cparity(m & 0xFu & (unsigned)i) << i;
        tb.chi[g] = c;
    }
    for (int w = 0; w < N_WIRES; ++w) {
        unsigned S = (1u << w) | (w >= 4 ? (1u << (w - 4)) : 0u) | (w >= 8 ? (1u << (w - 8)) : 0u);
        for (int g = 0; g < NGATES; ++g) tb.rel[w][g] = cparity(tb.gm[g] & S) != 0;
        unsigned lc = (w < 4) ? 0u
                    : (w < 8) ? (1u << (w - 4))
                    : ((1u << (w - 8)) | ((w - 4 < 6) ? (1u << (w - 4)) : 0u));
        tb.comp[w] = 0x3Fu & ~lc;
    }
    return tb;
}
constexpr Tabs TB = make_tabs();

// ---------------------------------------------------------------------------
// Single NON-cooperative launch, 256 blocks x 256 threads (1 block/CU; 1024
// waves << 8192-wave capacity => all blocks co-resident, spin cannot deadlock).
// Blocks 0..15: compute table slice i=blockIdx.x, publish to ws (transposed,
// agent-scope stores) + release-store sentinel flag[i]; hides under the other
// 240 blocks' x-load + GEMM. All blocks: R1-style GEMM; thread 0 acquire-spins
// the 16 flags (expected 0 iters); table summed via agent-scope relaxed loads
// (bypasses non-coherent L1/L2, Guideline 16); epilogue unchanged.
// Stale-flag across graph replays is benign: slices are params-only and
// identical every iteration; the per-iter ws poison fill resets flags anyway.
// ---------------------------------------------------------------------------
__global__ __launch_bounds__(256)
void fused_kernel(const float* __restrict__ x, const float* __restrict__ W,
                  const float* __restrict__ params, unsigned* __restrict__ ws,
                  float* __restrict__ out)
{
    __shared__ float xl[ROWS_PER_BLOCK * XSTRIDE];
    __shared__ float wl[N_WIRES * IN_DIM];
    __shared__ float al[ROWS_PER_BLOCK * N_WIRES];
    __shared__ float tabl[TABSZ];
    const int t = threadIdx.x;
    const int lane = t & 63;
    const int rowbase = blockIdx.x * ROWS_PER_BLOCK;

    // issue global loads up front; producer work / staging hides latency
    const float4* x4 = (const float4*)(x + (size_t)rowbase * IN_DIM);
    float4 xr[4];
    #pragma unroll
    for (int j = 0; j < 4; ++j) xr[j] = x4[t + 256 * j];
    const float4* W4 = (const float4*)W;
    float4 wr[3];
    #pragma unroll
    for (int j = 0; j < 3; ++j) wr[j] = W4[t + 256 * j];

    if (blockIdx.x < NSLICE) {
        // ---- producer: table slice for low nibble i; t = high 8 bits of k --
        const unsigned i = blockIdx.x;
        if (t < TABSZ) tabl[t] = 0.f;
        __syncthreads();   // block-uniform branch: barrier is legal

        float th[NGATES];
        #pragma unroll
        for (int g = 0; g < NGATES; ++g) {
            unsigned hs = (unsigned)(__popc((TB.gm[g] >> 4) & (unsigned)t) & 1);
            hs ^= (TB.chi[g] >> i) & 1u;
            th[g] = __int_as_float(__float_as_int(params[g]) ^ (int)(hs << 31));
        }
        float ca[N_WIRES], sa[N_WIRES];
        #pragma unroll
        for (int w = 0; w < N_WIRES; ++w) {
            float p = 0.f;
            #pragma unroll
            for (int g = 0; g < NGATES; ++g)
                if (TB.rel[w][g]) p += th[g];
            float sn, cs;
            __sincosf(p, &sn, &cs);
            ca[w] = cs; sa[w] = sn;
        }
        #pragma unroll
        for (int w = 0; w < N_WIRES; ++w) {
            const unsigned comp = TB.comp[w];
            float vc = ca[w], vs = sa[w];
            #pragma unroll
            for (int d = 0; d < 6; ++d) {
                if (comp & (1u << d)) {
                    vc += __shfl_xor(vc, 1 << d, 64);
                    vs += __shfl_xor(vs, 1 << d, 64);
                }
            }
            if ((unsigned)(lane & (int)comp) == 0u) {
                unsigned fk = 0;
                if (w >= 4 && w < 8) fk = ((unsigned)t >> (w - 4)) & 1u;
                if (w >= 8) fk = (((unsigned)t >> (w - 8)) & 1u)
                               | ((((unsigned)t >> (w - 4)) & 1u) << 1);
                const int b = (int)((i >> (w & 3)) & 1u);   // kap bit0 = k bit (w&3)
                atomicAdd(&tabl[w * 16 + (int)(fk << 1) + b],     vc);
                atomicAdd(&tabl[w * 16 + 8 + (int)(fk << 1) + b], vs);
            }
        }
        __syncthreads();
        // publish slice (transposed: ws[t*16+i]) at agent scope, then flag
        if (t < TABSZ)
            __hip_atomic_store(&ws[(size_t)t * NSLICE + i],
                               (unsigned)__float_as_int(tabl[t]),
                               __ATOMIC_RELAXED, __HIP_MEMORY_SCOPE_AGENT);
        __threadfence();
        if (t == 0)
            __hip_atomic_store(&ws[FLAG_OFF + i], SENTINEL,
                               __ATOMIC_RELEASE, __HIP_MEMORY_SCOPE_AGENT);
    }

    // ---- all blocks: stage x tile + W (regs -> LDS) ----
    #pragma unroll
    for (int j = 0; j < 4; ++j) {
        int f = t + 256 * j, row = f >> 6, c4 = f & 63;
        *(float4*)&xl[row * XSTRIDE + c4 * 4] = xr[j];
    }
    #pragma unroll
    for (int j = 0; j < 3; ++j) ((float4*)wl)[t + 256 * j] = wr[j];
    __syncthreads();

    // angles: 16 threads per row, xor-shuffle reduce (R1 measured-best shape)
    const int r = t >> 4, p = t & 15;
    float partial[N_WIRES];
    #pragma unroll
    for (int w = 0; w < N_WIRES; ++w) partial[w] = 0.f;
    for (int i2 = 0; i2 < 16; ++i2) {
        float xv = xl[r * XSTRIDE + i2 * 16 + p];
        #pragma unroll
        for (int w = 0; w < N_WIRES; ++w)
            partial[w] = fmaf(xv, wl[w * IN_DIM + i2 * 16 + p], partial[w]);
    }
    #pragma unroll
    for (int w = 0; w < N_WIRES; ++w) {
        float v = partial[w];
        v += __shfl_xor(v, 1, 16);
        v += __shfl_xor(v, 2, 16);
        v += __shfl_xor(v, 4, 16);
        v += __shfl_xor(v, 8, 16);
        partial[w] = v;
    }
    if (p < N_WIRES) al[r * N_WIRES + p] = partial[p];

    // wait for all 16 slices (expected already set: producers ran ~2 us ago)
    if (t == 0) {
        #pragma unroll 1
        for (int i = 0; i < NSLICE; ++i)
            while (__hip_atomic_load(&ws[FLAG_OFF + i],
                                     __ATOMIC_ACQUIRE, __HIP_MEMORY_SCOPE_AGENT)
                   != SENTINEL) { __builtin_amdgcn_s_sleep(1); }
    }
    __syncthreads();

    // sum the 16 per-i partials via agent-scope loads (L2-coherence safe)
    if (t < TABSZ) {
        float s = 0.f;
        #pragma unroll
        for (int i = 0; i < NSLICE; ++i) {
            unsigned u = __hip_atomic_load(&ws[(size_t)t * NSLICE + i],
                                           __ATOMIC_RELAXED, __HIP_MEMORY_SCOPE_AGENT);
            s += __int_as_float((int)u);
        }
        tabl[t] = s;
    }
    __syncthreads();

    // epilogue: one thread per (row, wire); S_w positions are {w&3, w-4, w}
    if (t < ROWS_PER_BLOCK * N_WIRES) {
        const int r2 = t / N_WIRES;
        const int w  = t - r2 * N_WIRES;
        const int nb = 1 + (w >= 4) + (w >= 8);
        const float a0 = al[r2 * N_WIRES + (w & 3)];
        const float a1 = (w >= 4) ? al[r2 * N_WIRES + ((w >= 8) ? (w - 4) : w)] : 0.f;
        const float a2 = (w >= 8) ? al[r2 * N_WIRES + w] : 0.f;
        float o = 0.f;
        const int nk = 1 << nb;
        for (int kap = 0; kap < nk; ++kap) {
            float B = (kap & 1) ? -a0 : a0;
            if (nb > 1) B += (kap & 2) ? -a1 : a1;
            if (nb > 2) B += (kap & 4) ? -a2 : a2;
            float sn, cs;
            __sincosf(B, &sn, &cs);
            o = fmaf(cs,  tabl[w * 16 + kap],     o);
            o = fmaf(-sn, tabl[w * 16 + 8 + kap], o);
        }
        out[(size_t)(rowbase + r2) * N_WIRES + w] = o * (1.f / 4096.f);
    }
}

extern "C" void kernel_launch(void* const* d_in, const int* in_sizes, int n_in,
                              void* d_out, int out_size, void* d_ws, size_t ws_size,
                              hipStream_t stream) {
    const float* x      = (const float*)d_in[0];
    const float* W      = (const float*)d_in[1];
    const float* params = (const float*)d_in[2];
    float* out          = (float*)d_out;
    unsigned* ws        = (unsigned*)d_ws;   // slices 12 KB + 16 flag words
    (void)n_in; (void)out_size; (void)ws_size;

    const int batch = in_sizes[0] / IN_DIM;
    hipLaunchKernelGGL(fused_kernel, dim3(batch / ROWS_PER_BLOCK), dim3(256), 0, stream,
                       x, W, params, ws, out);
}

// Round 5
// 66.095 us; speedup vs baseline: 1.6756x; 1.6756x over previous
//
#include <hip/hip_runtime.h>
#include <math.h>

#define N_WIRES 12
#define DEPTH   4
#define NGATES  48
#define IN_DIM  256
#define ROWS_PER_BLOCK 16
#define XSTRIDE 272     // 256 + 16 pad
#define TABSZ   (N_WIRES * 16)   // 192 floats: [w*16+kap]=C, [w*16+8+kap]=D
#define NSLICE  16

// ---- compile-time circuit structure (masks are data-independent) ----
// Gate (d,w): RX after d CNOT-chain layers; folded mask = col w of L^-d.
// L = lower-triangular ones; L^-1 = I+N (N = subdiagonal); L^-d = binomial mod 2.
// Measurement string S_w = row w of L^4 = {w, w-4, w-8} (>=0 only).
struct Tabs {
    unsigned gm[NGATES];          // gate masks
    bool     rel[N_WIRES][NGATES];// gate in G_w iff par(gm & S_w)
    unsigned chi[NGATES];         // bit i = par(gm_low_nibble & i), i=0..15
    unsigned comp[N_WIRES];       // butterfly dims = lane dims not in class
};
constexpr int cparity(unsigned v) { int c = 0; while (v) { c ^= (int)(v & 1u); v >>= 1; } return c; }
constexpr Tabs make_tabs() {
    Tabs tb{};
    for (int g = 0; g < NGATES; ++g) {
        int d = g / N_WIRES, w = g % N_WIRES;
        unsigned m = 1u << w;
        if ((d == 1 || d == 3) && w + 1 < N_WIRES) m |= 1u << (w + 1);
        if ((d == 2 || d == 3) && w + 2 < N_WIRES) m |= 1u << (w + 2);
        if (d == 3 && w + 3 < N_WIRES)             m |= 1u << (w + 3);
        tb.gm[g] = m;
        unsigned c = 0;
        for (int i = 0; i < 16; ++i) c |= (unsigned)cparity(m & 0xFu & (unsigned)i) << i;
        tb.chi[g] = c;
    }
    for (int w = 0; w < N_WIRES; ++w) {
        unsigned S = (1u << w) | (w >= 4 ? (1u << (w - 4)) : 0u) | (w >= 8 ? (1u << (w - 8)) : 0u);
        for (int g = 0; g < NGATES; ++g) tb.rel[w][g] = cparity(tb.gm[g] & S) != 0;
        unsigned lc = (w < 4) ? 0u
                    : (w < 8) ? (1u << (w - 4))
                    : ((1u << (w - 8)) | ((w - 4 < 6) ? (1u << (w - 4)) : 0u));
        tb.comp[w] = 0x3Fu & ~lc;
    }
    return tb;
}
constexpr Tabs TB = make_tabs();

// ---------------------------------------------------------------------------
// K1: params-only table, computed ONCE (two-kernel split is the measured-best
// structure: R1=66.4us; both single-kernel fusions cost +44us on cross-XCD
// visibility stalls). Grid = 16 blocks; block i handles low-nibble k value i;
// thread t = high 8 bits of k. Slice stored TRANSPOSED (ws[t*16+i]) so K2
// reads each entry's 16 partials as 4 x float4. Pure stores: no memset needed.
// ---------------------------------------------------------------------------
__global__ __launch_bounds__(256)
void tab_kernel(const float* __restrict__ params, float* __restrict__ ws)
{
    __shared__ float tab[TABSZ];
    const int t = threadIdx.x;
    const int lane = t & 63;
    const unsigned i = blockIdx.x;          // low nibble of k, 0..15

    if (t < TABSZ) tab[t] = 0.f;
    __syncthreads();

    // signed thetas: fold BOTH the hi-part (t) and lo-part (i) character signs
    float th[NGATES];
    #pragma unroll
    for (int g = 0; g < NGATES; ++g) {
        unsigned hs = (unsigned)(__popc((TB.gm[g] >> 4) & (unsigned)t) & 1);
        hs ^= (TB.chi[g] >> i) & 1u;
        th[g] = __int_as_float(__float_as_int(params[g]) ^ (int)(hs << 31));
    }

    // one phase + sincos per wire (signs pre-folded into th)
    float ca[N_WIRES], sa[N_WIRES];
    #pragma unroll
    for (int w = 0; w < N_WIRES; ++w) {
        float p = 0.f;
        #pragma unroll
        for (int g = 0; g < NGATES; ++g)
            if (TB.rel[w][g]) p += th[g];
        float sn, cs;
        __sincosf(p, &sn, &cs);
        ca[w] = cs; sa[w] = sn;
    }

    // butterfly over non-class lane dims, then few-lane LDS atomics
    #pragma unroll
    for (int w = 0; w < N_WIRES; ++w) {
        const unsigned comp = TB.comp[w];
        float vc = ca[w], vs = sa[w];
        #pragma unroll
        for (int d = 0; d < 6; ++d) {
            if (comp & (1u << d)) {
                vc += __shfl_xor(vc, 1 << d, 64);
                vs += __shfl_xor(vs, 1 << d, 64);
            }
        }
        if ((unsigned)(lane & (int)comp) == 0u) {
            unsigned fk = 0;
            if (w >= 4 && w < 8) fk = ((unsigned)t >> (w - 4)) & 1u;
            if (w >= 8) fk = (((unsigned)t >> (w - 8)) & 1u)
                           | ((((unsigned)t >> (w - 4)) & 1u) << 1);
            const int b = (int)((i >> (w & 3)) & 1u);   // kap bit0 = k bit (w&3)
            atomicAdd(&tab[w * 16 + (int)(fk << 1) + b],     vc);
            atomicAdd(&tab[w * 16 + 8 + (int)(fk << 1) + b], vs);
        }
    }
    __syncthreads();
    if (t < TABSZ) ws[(size_t)t * NSLICE + i] = tab[t];   // transposed
}

// ---------------------------------------------------------------------------
// K2: per-row work only (R1 measured-best shape) — sum the 16 table partials
// (3 KB, L2-broadcast, 4 x float4 each), angle GEMM via LDS, epilogue.
// ---------------------------------------------------------------------------
__global__ __launch_bounds__(256)
void main_kernel(const float* __restrict__ x, const float* __restrict__ W,
                 const float* __restrict__ tabg, float* __restrict__ out)
{
    __shared__ float xl[ROWS_PER_BLOCK * XSTRIDE];
    __shared__ float wl[N_WIRES * IN_DIM];
    __shared__ float al[ROWS_PER_BLOCK * N_WIRES];
    __shared__ float tab[TABSZ];
    const int t = threadIdx.x;
    const int rowbase = blockIdx.x * ROWS_PER_BLOCK;

    // issue global loads early
    const float4* x4 = (const float4*)(x + (size_t)rowbase * IN_DIM);
    float4 xr[4];
    #pragma unroll
    for (int j = 0; j < 4; ++j) xr[j] = x4[t + 256 * j];
    const float4* W4 = (const float4*)W;
    float4 wr[3];
    #pragma unroll
    for (int j = 0; j < 3; ++j) wr[j] = W4[t + 256 * j];

    // sum the 16 per-i partials (contiguous after K1's transpose)
    if (t < TABSZ) {
        const float4* p4 = (const float4*)(tabg + (size_t)t * NSLICE);
        float4 s0 = p4[0], s1 = p4[1], s2 = p4[2], s3 = p4[3];
        tab[t] = ((s0.x + s0.y) + (s0.z + s0.w)) + ((s1.x + s1.y) + (s1.z + s1.w))
               + ((s2.x + s2.y) + (s2.z + s2.w)) + ((s3.x + s3.y) + (s3.z + s3.w));
    }

    // stage x tile + W (regs -> LDS)
    #pragma unroll
    for (int j = 0; j < 4; ++j) {
        int f = t + 256 * j, row = f >> 6, c4 = f & 63;
        *(float4*)&xl[row * XSTRIDE + c4 * 4] = xr[j];
    }
    #pragma unroll
    for (int j = 0; j < 3; ++j) ((float4*)wl)[t + 256 * j] = wr[j];
    __syncthreads();

    // angles: 16 threads per row, xor-shuffle reduce
    const int r = t >> 4, p = t & 15;
    float partial[N_WIRES];
    #pragma unroll
    for (int w = 0; w < N_WIRES; ++w) partial[w] = 0.f;
    for (int i2 = 0; i2 < 16; ++i2) {
        float xv = xl[r * XSTRIDE + i2 * 16 + p];
        #pragma unroll
        for (int w = 0; w < N_WIRES; ++w)
            partial[w] = fmaf(xv, wl[w * IN_DIM + i2 * 16 + p], partial[w]);
    }
    #pragma unroll
    for (int w = 0; w < N_WIRES; ++w) {
        float v = partial[w];
        v += __shfl_xor(v, 1, 16);
        v += __shfl_xor(v, 2, 16);
        v += __shfl_xor(v, 4, 16);
        v += __shfl_xor(v, 8, 16);
        partial[w] = v;
    }
    if (p < N_WIRES) al[r * N_WIRES + p] = partial[p];
    __syncthreads();

    // epilogue: one thread per (row, wire); S_w positions are {w&3, w-4, w}
    if (t < ROWS_PER_BLOCK * N_WIRES) {
        const int r2 = t / N_WIRES;
        const int w  = t - r2 * N_WIRES;
        const int nb = 1 + (w >= 4) + (w >= 8);
        const float a0 = al[r2 * N_WIRES + (w & 3)];
        const float a1 = (w >= 4) ? al[r2 * N_WIRES + ((w >= 8) ? (w - 4) : w)] : 0.f;
        const float a2 = (w >= 8) ? al[r2 * N_WIRES + w] : 0.f;
        float o = 0.f;
        const int nk = 1 << nb;
        for (int kap = 0; kap < nk; ++kap) {
            float B = (kap & 1) ? -a0 : a0;
            if (nb > 1) B += (kap & 2) ? -a1 : a1;
            if (nb > 2) B += (kap & 4) ? -a2 : a2;
            float sn, cs;
            __sincosf(B, &sn, &cs);
            o = fmaf(cs,  tab[w * 16 + kap],     o);
            o = fmaf(-sn, tab[w * 16 + 8 + kap], o);
        }
        out[(size_t)(rowbase + r2) * N_WIRES + w] = o * (1.f / 4096.f);
    }
}

extern "C" void kernel_launch(void* const* d_in, const int* in_sizes, int n_in,
                              void* d_out, int out_size, void* d_ws, size_t ws_size,
                              hipStream_t stream) {
    const float* x      = (const float*)d_in[0];
    const float* W      = (const float*)d_in[1];
    const float* params = (const float*)d_in[2];
    float* out          = (float*)d_out;
    float* ws           = (float*)d_ws;   // 192*16 floats = 12 KB used
    (void)n_in; (void)out_size; (void)ws_size;

    const int batch = in_sizes[0] / IN_DIM;
    hipLaunchKernelGGL(tab_kernel,  dim3(NSLICE),                 dim3(256), 0, stream,
                       params, ws);
    hipLaunchKernelGGL(main_kernel, dim3(batch / ROWS_PER_BLOCK), dim3(256), 0, stream,
                       x, W, ws, out);
}